// Round 1
// baseline (120.245 us; speedup 1.0000x reference)
//
#include <hip/hip_runtime.h>
#include <hip/hip_bf16.h>

typedef __attribute__((ext_vector_type(8))) short short8;
typedef __attribute__((ext_vector_type(4))) float f32x4;
typedef __attribute__((address_space(1))) const void gvoid_t;
typedef __attribute__((address_space(3))) void lvoid_t;

#define NB 4096   // B
#define DD 256    // D
#define TWOB 8192
#define NMACRO 1056u   // sum_{tr} (32 - tr/2) macro 128x256 tiles
#define GSUM_BLOCKS 16
#define NPART 1072     // gsum + macro participants (spares excluded)

__device__ __forceinline__ unsigned short f2bf(float f) {
  unsigned int u = __float_as_uint(f);
  u += 0x7fffu + ((u >> 16) & 1u);
  return (unsigned short)(u >> 16);
}
__device__ __forceinline__ float bf2f(unsigned short s) {
  return __uint_as_float(((unsigned int)s) << 16);
}

// ws layout (bytes):
//   [0, 32768)          den[8192] f32 (zeroed by norm blocks 0..31)
//   [32768, 32772)      done counter (zeroed by norm block 32)
//   [65536, 4259840)    znb 8192x256 bf16
//   [4259840, 4276224)  vsum_part[16][4][256] f32
//   [4276224, 4276480)  cnt_part[16][4] int
//   [4276480, 4280576)  ppos[1024] f32
//
// R18: K-loop rebuilt as counted-vmcnt pipeline (T4): 3 LDS buffers, raw
// s_barrier once per K-step, s_waitcnt vmcnt(6) instead of the
// __syncthreads vmcnt(0) drain. stage(kt+2) overwrites buffer (kt-1)%3,
// safe because every wave's kt-1 ds_reads are complete before its MFMAs
// issue (compiler lgkmcnt), hence before it reaches the top-of-kt barrier.
// setprio(1) around MFMA clusters (T5). tail_kernel fused into den_kernel
// via done-counter; agent-scope fences/loads for cross-XCD visibility.

// ---------------- kernel A: zero den+counter; normalize -> znb; ppos ------
__global__ __launch_bounds__(256) void norm_kernel(const float* __restrict__ zi,
                                                   const float* __restrict__ zj,
                                                   float* __restrict__ wsf,
                                                   float* __restrict__ ppos,
                                                   unsigned short* __restrict__ znb) {
  __shared__ float sred[4];
  if (blockIdx.x < 32) wsf[blockIdx.x * 256 + threadIdx.x] = 0.f;
  if (blockIdx.x == 32 && threadIdx.x == 0) ((int*)(wsf + 8192))[0] = 0;  // done cnt
  const int lane = threadIdx.x & 63, wave = threadIdx.x >> 6;
  const int i = blockIdx.x * 4 + wave;

  float4 a = ((const float4*)(zi + (size_t)i * DD))[lane];
  float4 b = ((const float4*)(zj + (size_t)i * DD))[lane];
  float sa = a.x * a.x + a.y * a.y + a.z * a.z + a.w * a.w;
  float sb = b.x * b.x + b.y * b.y + b.z * b.z + b.w * b.w;
  float sab = a.x * b.x + a.y * b.y + a.z * b.z + a.w * b.w;
#pragma unroll
  for (int m = 32; m >= 1; m >>= 1) {
    sa += __shfl_xor(sa, m);
    sb += __shfl_xor(sb, m);
    sab += __shfl_xor(sab, m);
  }
  float ra = 1.0f / fmaxf(sqrtf(sa), 1e-8f);
  float rb = 1.0f / fmaxf(sqrtf(sb), 1e-8f);
  ushort4 oa, ob;
  oa.x = f2bf(a.x * ra); oa.y = f2bf(a.y * ra); oa.z = f2bf(a.z * ra); oa.w = f2bf(a.w * ra);
  ob.x = f2bf(b.x * rb); ob.y = f2bf(b.y * rb); ob.z = f2bf(b.z * rb); ob.w = f2bf(b.w * rb);
  ((ushort4*)(znb + (size_t)i * DD))[lane] = oa;
  ((ushort4*)(znb + (size_t)(i + NB) * DD))[lane] = ob;

  if (lane == 0) sred[wave] = sab * ra * rb;  // exact fp32 pos (row i)
  __syncthreads();
  if (threadIdx.x == 0)
    ppos[blockIdx.x] = sred[0] + sred[1] + sred[2] + sred[3];
}

// ---------------- kernel B: gsum + macro den tiles + fused tail -----------
__global__ __launch_bounds__(256, 2) void den_kernel(const int* __restrict__ sf,
                                                     float* __restrict__ wsf,
                                                     const unsigned short* __restrict__ znb,
                                                     float* __restrict__ vsum_part,
                                                     int* __restrict__ cnt_part,
                                                     const float* __restrict__ ppos,
                                                     float* __restrict__ out,
                                                     int* __restrict__ done_cnt) {
  __shared__ __align__(16) unsigned short As[3][4096];  // 24 KB (A: 128 rows, 3 bufs)
  __shared__ __align__(16) unsigned short Bs[3][8192];  // 48 KB (B: 256 cols, 3 bufs)
  __shared__ int islast;

  float* den = wsf;

  const int tid = threadIdx.x;
  const int lane = tid & 63, wave = tid >> 6;
  const unsigned t_lin = blockIdx.y * 64u + blockIdx.x;

  if (t_lin >= NMACRO + GSUM_BLOCKS) return;  // spares (not counted in NPART)

  if (t_lin < GSUM_BLOCKS) {
    // ---- gsum: 256 rows, LDS reduce, plain stores (unchanged) -----------
    const int b = (int)t_lin;
    const int r0 = b * 256;
    float acc[4][4];
#pragma unroll
    for (int q = 0; q < 4; ++q)
#pragma unroll
      for (int e = 0; e < 4; ++e) acc[q][e] = 0.f;
    int cnt[4] = {0, 0, 0, 0};
    const int rw = r0 + wave * 64;
    for (int k = 0; k < 64; ++k) {
      int row = rw + k;
      int g = sf[row];
      ushort4 v = ((const ushort4*)(znb + (size_t)row * DD))[lane];
      float f0 = bf2f(v.x), f1 = bf2f(v.y), f2 = bf2f(v.z), f3 = bf2f(v.w);
#pragma unroll
      for (int q = 0; q < 4; ++q) {
        bool sel = (g == q);
        acc[q][0] += sel ? f0 : 0.f;
        acc[q][1] += sel ? f1 : 0.f;
        acc[q][2] += sel ? f2 : 0.f;
        acc[q][3] += sel ? f3 : 0.f;
        cnt[q] += sel ? 1 : 0;
      }
    }
    float4* lsd = (float4*)&As[0][0];
    int* lcnt = (int*)&Bs[0][0];
#pragma unroll
    for (int q = 0; q < 4; ++q) {
      float4 t;
      t.x = acc[q][0]; t.y = acc[q][1]; t.z = acc[q][2]; t.w = acc[q][3];
      lsd[(wave * 4 + q) * 64 + lane] = t;
    }
    if (lane == 0) {
#pragma unroll
      for (int q = 0; q < 4; ++q) lcnt[wave * 4 + q] = cnt[q];
    }
    __syncthreads();
    {
      int g = tid >> 6, l = tid & 63;
      float4 s0 = lsd[(0 + g) * 64 + l];
      float4 s1 = lsd[(4 + g) * 64 + l];
      float4 s2 = lsd[(8 + g) * 64 + l];
      float4 s3 = lsd[(12 + g) * 64 + l];
      float4 s;
      s.x = s0.x + s1.x + s2.x + s3.x;
      s.y = s0.y + s1.y + s2.y + s3.y;
      s.z = s0.z + s1.z + s2.z + s3.z;
      s.w = s0.w + s1.w + s2.w + s3.w;
      ((float4*)(vsum_part + (size_t)(b * 4 + g) * 256))[l] = s;
      if (tid < 4)
        cnt_part[b * 4 + tid] = lcnt[tid] + lcnt[4 + tid] + lcnt[8 + tid] + lcnt[12 + tid];
    }
  } else {
    // ---- one 128x256 macro tile ----------------------------------------
    unsigned t = t_lin - GSUM_BLOCKS;
    unsigned tr = 0;
    while (t >= 32u - (tr >> 1)) { t -= 32u - (tr >> 1); ++tr; }
    unsigned c = (tr >> 1) + t;
    const size_t rowbase = (size_t)tr * 128;
    const size_t colbase = (size_t)c * 256;
    const int tc0 = (int)(2 * c), tc1 = (int)(2 * c + 1);

    const int u = lane >> 3;
    const int cp = (lane & 7) ^ u;
    const int ri = 2 * u + (cp >> 2);
    const int kelem = (cp & 3) * 8;
    const int slot = ((((lane & 1) << 2) | (lane >> 4)) ^ ((lane >> 1) & 7));
    const int fragoff = ((lane & 15) >> 1) * 128 + slot * 16;
    const int wrow = wave & 1, wcol = wave >> 1;

    const int tch = wcol ? tc1 : tc0;
    const float fr = (tch >= (int)tr) ? 1.f : 0.f;  // include in row sums
    const float fc = (tch > (int)tr) ? 1.f : 0.f;   // include in col sums

    f32x4 zero = {0.f, 0.f, 0.f, 0.f};
    f32x4 acc[4][8];
#pragma unroll
    for (int i = 0; i < 4; ++i)
#pragma unroll
      for (int j = 0; j < 8; ++j) acc[i][j] = zero;

    auto stage = [&](int kt, int buf) {
#pragma unroll
      for (int j = 0; j < 2; ++j) {
        int is = wave * 2 + j;
        const unsigned short* gpa = znb + (rowbase + is * 16 + ri) * DD + kt * 32 + kelem;
        __builtin_amdgcn_global_load_lds((gvoid_t*)gpa, (lvoid_t*)&As[buf][is * 512], 16, 0, 0);
      }
#pragma unroll
      for (int j = 0; j < 4; ++j) {
        int is = wave * 4 + j;
        const unsigned short* gpb = znb + (colbase + is * 16 + ri) * DD + kt * 32 + kelem;
        __builtin_amdgcn_global_load_lds((gvoid_t*)gpb, (lvoid_t*)&Bs[buf][is * 512], 16, 0, 0);
      }
    };

    // counted-vmcnt pipeline: stage k always lands in buffer k%3.
    stage(0, 0);
    stage(1, 1);
#pragma unroll
    for (int kt = 0; kt < 8; ++kt) {
      const int buf = kt % 3;
      // wait for stage(kt): 6 loads of stage(kt+1) may stay in flight
      if (kt < 7) asm volatile("s_waitcnt vmcnt(6)" ::: "memory");
      else        asm volatile("s_waitcnt vmcnt(0)" ::: "memory");
      __builtin_amdgcn_s_barrier();       // all waves' stage(kt) landed
      asm volatile("" ::: "memory");
      short8 af[4], bfr[8];
#pragma unroll
      for (int mi = 0; mi < 4; ++mi)
        af[mi] = *(const short8*)((const char*)&As[0][0] + buf * 8192 + wrow * 4096 + mi * 1024 + fragoff);
#pragma unroll
      for (int ni = 0; ni < 8; ++ni)
        bfr[ni] = *(const short8*)((const char*)&Bs[0][0] + buf * 16384 + wcol * 8192 + ni * 1024 + fragoff);
      // overwrite buffer (kt+2)%3 == (kt-1)%3: freed because every wave's
      // kt-1 reads completed before its kt-1 MFMAs, i.e. before this barrier.
      if (kt < 6) stage(kt + 2, (kt + 2) % 3);
      __builtin_amdgcn_s_setprio(1);
#pragma unroll
      for (int mi = 0; mi < 4; ++mi)
#pragma unroll
        for (int ni = 0; ni < 8; ++ni)
          acc[mi][ni] = __builtin_amdgcn_mfma_f32_16x16x32_bf16(af[mi], bfr[ni], acc[mi][ni], 0, 0, 0);
      __builtin_amdgcn_s_setprio(0);
      asm volatile("" ::: "memory");
    }

    // epilogue: e = exp(2S); row/col sums with wave-uniform fr/fc; combine in
    // LDS; atomics. C layout: col=lane&15, row=(lane>>4)*4+reg.
    float rsum[4][4];
    float csum[8];
#pragma unroll
    for (int mi = 0; mi < 4; ++mi)
#pragma unroll
      for (int r = 0; r < 4; ++r) rsum[mi][r] = 0.f;
#pragma unroll
    for (int ni = 0; ni < 8; ++ni) csum[ni] = 0.f;
#pragma unroll
    for (int mi = 0; mi < 4; ++mi)
#pragma unroll
      for (int ni = 0; ni < 8; ++ni)
#pragma unroll
        for (int r = 0; r < 4; ++r) {
          float e = __expf(2.0f * acc[mi][ni][r]);
          rsum[mi][r] += e;
          csum[ni] += e;
        }
#pragma unroll
    for (int m = 1; m < 16; m <<= 1)
#pragma unroll
      for (int mi = 0; mi < 4; ++mi)
#pragma unroll
        for (int r = 0; r < 4; ++r) rsum[mi][r] += __shfl_xor(rsum[mi][r], m);
#pragma unroll
    for (int m = 16; m < 64; m <<= 1)
#pragma unroll
      for (int ni = 0; ni < 8; ++ni) csum[ni] += __shfl_xor(csum[ni], m);

    float* Lr = (float*)&As[0][0];  // [2][128] indexed by wcol (bytes 0..1023)
    float* Lc = Lr + 256;           // [2][256] indexed by wrow (bytes 1024..3071)
    if ((lane & 15) == 0) {
      int h = lane >> 4;
#pragma unroll
      for (int mi = 0; mi < 4; ++mi)
#pragma unroll
        for (int r = 0; r < 4; ++r)
          Lr[wcol * 128 + wrow * 64 + mi * 16 + h * 4 + r] = rsum[mi][r] * fr;
    }
    if (lane < 16) {
#pragma unroll
      for (int ni = 0; ni < 8; ++ni)
        Lc[wrow * 256 + wcol * 128 + ni * 16 + lane] = csum[ni] * fc;
    }
    __syncthreads();
    if (tid < 128) {
      unsafeAtomicAdd(&den[rowbase + tid], Lr[tid] + Lr[128 + tid]);
    }
    {
      float v = Lc[tid] + Lc[256 + tid];
      if (v != 0.f) unsafeAtomicAdd(&den[colbase + tid], v);
    }
  }

  // ---------------- completion protocol + fused tail ----------------------
  __syncthreads();                 // drains each wave's outstanding stores/atomics
  if (tid == 0) {
    __threadfence();               // writeback this XCD's L2 (release)
    int prev = atomicAdd(done_cnt, 1);
    islast = (prev == NPART - 1) ? 1 : 0;
  }
  __syncthreads();
  if (islast == 0) return;
  if (tid == 0) __threadfence();   // invalidate caches (acquire)
  __syncthreads();

  {
    float* sred = (float*)&Bs[0][0];
    const float e2 = __expf(2.0f);
    float ls = 0.f;
    for (int i = tid; i < TWOB; i += 256) {
      float d = __hip_atomic_load(&wsf[i], __ATOMIC_RELAXED, __HIP_MEMORY_SCOPE_AGENT);
      ls += __logf(d - e2);
    }
#pragma unroll
    for (int m = 32; m >= 1; m >>= 1) ls += __shfl_xor(ls, m);
    if (lane == 0) sred[wave] = ls;

    float pp = 0.f;
#pragma unroll
    for (int k = 0; k < 4; ++k) pp += ppos[k * 256 + tid];
#pragma unroll
    for (int m = 32; m >= 1; m >>= 1) pp += __shfl_xor(pp, m);
    if (lane == 0) sred[4 + wave] = pp;

    float gp[4];
#pragma unroll
    for (int g = 0; g < 4; ++g) {
      float v = 0.f;
#pragma unroll
      for (int b = 0; b < 16; ++b)
        v += __hip_atomic_load(&vsum_part[(size_t)(b * 4 + g) * 256 + tid],
                               __ATOMIC_RELAXED, __HIP_MEMORY_SCOPE_AGENT);
      gp[g] = v * v;
#pragma unroll
      for (int m = 32; m >= 1; m >>= 1) gp[g] += __shfl_xor(gp[g], m);
    }
    if (lane == 0) {
#pragma unroll
      for (int g = 0; g < 4; ++g) sred[8 + wave * 4 + g] = gp[g];
    }
    __syncthreads();
    if (tid == 0) {
      float lsum = sred[0] + sred[1] + sred[2] + sred[3];
      float psum = sred[4] + sred[5] + sred[6] + sred[7];
      float contrastive = (lsum - 4.0f * psum) / (float)TWOB;
      float fsum = 0.f;
      int uniq = 0;
#pragma unroll
      for (int q = 0; q < 4; ++q) {
        int ci = 0;
#pragma unroll
        for (int b = 0; b < 16; ++b)
          ci += __hip_atomic_load(&cnt_part[b * 4 + q],
                                  __ATOMIC_RELAXED, __HIP_MEMORY_SCOPE_AGENT);
        float gsq = sred[8 + q] + sred[12 + q] + sred[16 + q] + sred[20 + q];
        float cf = (float)ci;
        if (ci > 0) uniq++;
        if (ci > 1) fsum += gsq / (cf * (cf - 1.0f));
      }
      out[0] = contrastive + 0.1f * (fsum / (uniq > 0 ? (float)uniq : 1.0f));
    }
  }
}

extern "C" void kernel_launch(void* const* d_in, const int* in_sizes, int n_in,
                              void* d_out, int out_size, void* d_ws, size_t ws_size,
                              hipStream_t stream) {
  const float* zi = (const float*)d_in[0];
  const float* zj = (const float*)d_in[1];
  const int* sf = (const int*)d_in[2];
  float* out = (float*)d_out;
  char* ws = (char*)d_ws;
  float* wsf = (float*)ws;                              // den
  int* done_cnt = (int*)(ws + 32768);                   // completion counter
  unsigned short* znb = (unsigned short*)(ws + 65536);  // 8192x256 bf16 (4MB)
  float* vsum_part = (float*)(ws + 4259840);            // 16x4x256 f32
  int* cnt_part = (int*)(ws + 4276224);                 // 16x4 int
  float* ppos = (float*)(ws + 4276480);                 // 1024 f32

  hipLaunchKernelGGL(norm_kernel, dim3(1024), dim3(256), 0, stream, zi, zj, wsf, ppos, znb);
  hipLaunchKernelGGL(den_kernel, dim3(64, 17), dim3(256), 0, stream,
                     sf, wsf, znb, vsum_part, cnt_part, ppos, out, done_cnt);
}

// Round 2
// 116.805 us; speedup vs baseline: 1.0294x; 1.0294x over previous
//
#include <hip/hip_runtime.h>
#include <hip/hip_bf16.h>

typedef __attribute__((ext_vector_type(8))) short short8;
typedef __attribute__((ext_vector_type(4))) float f32x4;
typedef __attribute__((address_space(1))) const void gvoid_t;
typedef __attribute__((address_space(3))) void lvoid_t;

#define NB 4096   // B
#define DD 256    // D
#define TWOB 8192
#define NMACRO 1056u   // sum_{tr} (32 - tr/2) macro 128x256 tiles
#define GSUM_BLOCKS 16

__device__ __forceinline__ unsigned short f2bf(float f) {
  unsigned int u = __float_as_uint(f);
  u += 0x7fffu + ((u >> 16) & 1u);
  return (unsigned short)(u >> 16);
}
__device__ __forceinline__ float bf2f(unsigned short s) {
  return __uint_as_float(((unsigned int)s) << 16);
}

// ws layout (bytes):
//   [0, 256)            lsred[64] f32          (written by denred)
//   [1024, 5120)        ppos[1024] f32         (written by norm)
//   [8192, 8448)        cnt_part[16][4] int    (written by den/gsum)
//   [16384, 32768)      vsum_part[16][4][256]  (written by den/gsum)
//   [65536, 4259840)    znb 8192x256 bf16      (written by norm)
//   [4259840, 5308416)  rowpart[64][32][128]   (written by den/macro)
//   [5308416, 7405568)  colpart[32][64][256]   (written by den/macro)
//
// R19: R18's fence-storm + occupancy regression reverted (back to R17's
// 2-buffer __syncthreads K-loop, 48 KB LDS, separate tail). Single change
// vs R17: den's 354K global f32 atomics onto den[8192] are replaced with
// plain coalesced partial stores (rowpart/colpart, exact-cover disjoint
// slots) + a 64-block denred kernel that reduces partials and emits
// per-block sum of log(den - e^2). Isolates the atomic-storm theory.

// ---------------- kernel A: normalize -> znb bf16; ppos -------------------
__global__ __launch_bounds__(256) void norm_kernel(const float* __restrict__ zi,
                                                   const float* __restrict__ zj,
                                                   float* __restrict__ ppos,
                                                   unsigned short* __restrict__ znb) {
  __shared__ float sred[4];
  const int lane = threadIdx.x & 63, wave = threadIdx.x >> 6;
  const int i = blockIdx.x * 4 + wave;

  float4 a = ((const float4*)(zi + (size_t)i * DD))[lane];
  float4 b = ((const float4*)(zj + (size_t)i * DD))[lane];
  float sa = a.x * a.x + a.y * a.y + a.z * a.z + a.w * a.w;
  float sb = b.x * b.x + b.y * b.y + b.z * b.z + b.w * b.w;
  float sab = a.x * b.x + a.y * b.y + a.z * b.z + a.w * b.w;
#pragma unroll
  for (int m = 32; m >= 1; m >>= 1) {
    sa += __shfl_xor(sa, m);
    sb += __shfl_xor(sb, m);
    sab += __shfl_xor(sab, m);
  }
  float ra = 1.0f / fmaxf(sqrtf(sa), 1e-8f);
  float rb = 1.0f / fmaxf(sqrtf(sb), 1e-8f);
  ushort4 oa, ob;
  oa.x = f2bf(a.x * ra); oa.y = f2bf(a.y * ra); oa.z = f2bf(a.z * ra); oa.w = f2bf(a.w * ra);
  ob.x = f2bf(b.x * rb); ob.y = f2bf(b.y * rb); ob.z = f2bf(b.z * rb); ob.w = f2bf(b.w * rb);
  ((ushort4*)(znb + (size_t)i * DD))[lane] = oa;
  ((ushort4*)(znb + (size_t)(i + NB) * DD))[lane] = ob;

  if (lane == 0) sred[wave] = sab * ra * rb;  // exact fp32 pos (row i)
  __syncthreads();
  if (threadIdx.x == 0)
    ppos[blockIdx.x] = sred[0] + sred[1] + sred[2] + sred[3];
}

// ---------------- kernel B: gsum + 128x256 macro tiles (partial stores) ---
__global__ __launch_bounds__(256, 2) void den_kernel(const int* __restrict__ sf,
                                                     const unsigned short* __restrict__ znb,
                                                     float* __restrict__ vsum_part,
                                                     int* __restrict__ cnt_part,
                                                     float* __restrict__ rowpart,
                                                     float* __restrict__ colpart) {
  __shared__ __align__(16) unsigned short As[2][4096];  // 16 KB (A: 128 rows)
  __shared__ __align__(16) unsigned short Bs[2][8192];  // 32 KB (B: 256 cols)

  const int tid = threadIdx.x;
  const int lane = tid & 63, wave = tid >> 6;
  const unsigned t_lin = blockIdx.y * 64u + blockIdx.x;

  if (t_lin < GSUM_BLOCKS) {
    // ---- gsum: 256 rows, LDS reduce, plain stores (unchanged) -----------
    const int b = (int)t_lin;
    const int r0 = b * 256;
    float acc[4][4];
#pragma unroll
    for (int q = 0; q < 4; ++q)
#pragma unroll
      for (int e = 0; e < 4; ++e) acc[q][e] = 0.f;
    int cnt[4] = {0, 0, 0, 0};
    const int rw = r0 + wave * 64;
    for (int k = 0; k < 64; ++k) {
      int row = rw + k;
      int g = sf[row];
      ushort4 v = ((const ushort4*)(znb + (size_t)row * DD))[lane];
      float f0 = bf2f(v.x), f1 = bf2f(v.y), f2 = bf2f(v.z), f3 = bf2f(v.w);
#pragma unroll
      for (int q = 0; q < 4; ++q) {
        bool sel = (g == q);
        acc[q][0] += sel ? f0 : 0.f;
        acc[q][1] += sel ? f1 : 0.f;
        acc[q][2] += sel ? f2 : 0.f;
        acc[q][3] += sel ? f3 : 0.f;
        cnt[q] += sel ? 1 : 0;
      }
    }
    float4* lsd = (float4*)&As[0][0];
    int* lcnt = (int*)&Bs[0][0];
#pragma unroll
    for (int q = 0; q < 4; ++q) {
      float4 t;
      t.x = acc[q][0]; t.y = acc[q][1]; t.z = acc[q][2]; t.w = acc[q][3];
      lsd[(wave * 4 + q) * 64 + lane] = t;
    }
    if (lane == 0) {
#pragma unroll
      for (int q = 0; q < 4; ++q) lcnt[wave * 4 + q] = cnt[q];
    }
    __syncthreads();
    {
      int g = tid >> 6, l = tid & 63;
      float4 s0 = lsd[(0 + g) * 64 + l];
      float4 s1 = lsd[(4 + g) * 64 + l];
      float4 s2 = lsd[(8 + g) * 64 + l];
      float4 s3 = lsd[(12 + g) * 64 + l];
      float4 s;
      s.x = s0.x + s1.x + s2.x + s3.x;
      s.y = s0.y + s1.y + s2.y + s3.y;
      s.z = s0.z + s1.z + s2.z + s3.z;
      s.w = s0.w + s1.w + s2.w + s3.w;
      ((float4*)(vsum_part + (size_t)(b * 4 + g) * 256))[l] = s;
      if (tid < 4)
        cnt_part[b * 4 + tid] = lcnt[tid] + lcnt[4 + tid] + lcnt[8 + tid] + lcnt[12 + tid];
    }
    return;
  }
  if (t_lin >= NMACRO + GSUM_BLOCKS) return;  // spares

  // ---- one 128x256 macro tile (R17 K-loop, verbatim) ---------------------
  unsigned t = t_lin - GSUM_BLOCKS;
  unsigned tr = 0;
  while (t >= 32u - (tr >> 1)) { t -= 32u - (tr >> 1); ++tr; }
  unsigned c = (tr >> 1) + t;
  const size_t rowbase = (size_t)tr * 128;
  const size_t colbase = (size_t)c * 256;
  const int tc0 = (int)(2 * c), tc1 = (int)(2 * c + 1);

  const int u = lane >> 3;
  const int cp = (lane & 7) ^ u;
  const int ri = 2 * u + (cp >> 2);
  const int kelem = (cp & 3) * 8;
  const int slot = ((((lane & 1) << 2) | (lane >> 4)) ^ ((lane >> 1) & 7));
  const int fragoff = ((lane & 15) >> 1) * 128 + slot * 16;
  const int wrow = wave & 1, wcol = wave >> 1;

  // wave-uniform symmetry flags for this wave's 128-col half
  const int tch = wcol ? tc1 : tc0;
  const float fr = (tch >= (int)tr) ? 1.f : 0.f;  // include in row sums
  const float fc = (tch > (int)tr) ? 1.f : 0.f;   // include in col sums

  f32x4 zero = {0.f, 0.f, 0.f, 0.f};
  f32x4 acc[4][8];
#pragma unroll
  for (int i = 0; i < 4; ++i)
#pragma unroll
    for (int j = 0; j < 8; ++j) acc[i][j] = zero;

  auto stage = [&](int kt, int buf) {
#pragma unroll
    for (int j = 0; j < 2; ++j) {
      int is = wave * 2 + j;
      const unsigned short* gpa = znb + (rowbase + is * 16 + ri) * DD + kt * 32 + kelem;
      __builtin_amdgcn_global_load_lds((gvoid_t*)gpa, (lvoid_t*)&As[buf][is * 512], 16, 0, 0);
    }
#pragma unroll
    for (int j = 0; j < 4; ++j) {
      int is = wave * 4 + j;
      const unsigned short* gpb = znb + (colbase + is * 16 + ri) * DD + kt * 32 + kelem;
      __builtin_amdgcn_global_load_lds((gvoid_t*)gpb, (lvoid_t*)&Bs[buf][is * 512], 16, 0, 0);
    }
  };

  stage(0, 0);
  __syncthreads();
#pragma unroll
  for (int kt = 0; kt < 8; ++kt) {
    if (kt < 7) stage(kt + 1, (kt + 1) & 1);
    const int buf = kt & 1;
    short8 af[4], bfr[8];
#pragma unroll
    for (int mi = 0; mi < 4; ++mi)
      af[mi] = *(const short8*)((const char*)&As[0][0] + buf * 8192 + wrow * 4096 + mi * 1024 + fragoff);
#pragma unroll
    for (int ni = 0; ni < 8; ++ni)
      bfr[ni] = *(const short8*)((const char*)&Bs[0][0] + buf * 16384 + wcol * 8192 + ni * 1024 + fragoff);
#pragma unroll
    for (int mi = 0; mi < 4; ++mi)
#pragma unroll
      for (int ni = 0; ni < 8; ++ni)
        acc[mi][ni] = __builtin_amdgcn_mfma_f32_16x16x32_bf16(af[mi], bfr[ni], acc[mi][ni], 0, 0, 0);
    __syncthreads();
  }

  // epilogue: e = exp(2S); row/col sums with wave-uniform fr/fc; combine in
  // LDS; then PLAIN partial stores (no atomics).
  // C layout: col=lane&15, row=(lane>>4)*4+reg.
  float rsum[4][4];
  float csum[8];
#pragma unroll
  for (int mi = 0; mi < 4; ++mi)
#pragma unroll
    for (int r = 0; r < 4; ++r) rsum[mi][r] = 0.f;
#pragma unroll
  for (int ni = 0; ni < 8; ++ni) csum[ni] = 0.f;
#pragma unroll
  for (int mi = 0; mi < 4; ++mi)
#pragma unroll
    for (int ni = 0; ni < 8; ++ni)
#pragma unroll
      for (int r = 0; r < 4; ++r) {
        float e = __expf(2.0f * acc[mi][ni][r]);
        rsum[mi][r] += e;
        csum[ni] += e;
      }
#pragma unroll
  for (int m = 1; m < 16; m <<= 1)
#pragma unroll
    for (int mi = 0; mi < 4; ++mi)
#pragma unroll
      for (int r = 0; r < 4; ++r) rsum[mi][r] += __shfl_xor(rsum[mi][r], m);
#pragma unroll
  for (int m = 16; m < 64; m <<= 1)
#pragma unroll
    for (int ni = 0; ni < 8; ++ni) csum[ni] += __shfl_xor(csum[ni], m);

  float* Lr = (float*)&As[0][0];  // [2][128] indexed by wcol
  float* Lc = Lr + 256;           // [2][256] indexed by wrow
  if ((lane & 15) == 0) {
    int h = lane >> 4;
#pragma unroll
    for (int mi = 0; mi < 4; ++mi)
#pragma unroll
      for (int r = 0; r < 4; ++r)
        Lr[wcol * 128 + wrow * 64 + mi * 16 + h * 4 + r] = rsum[mi][r] * fr;
  }
  if (lane < 16) {
#pragma unroll
    for (int ni = 0; ni < 8; ++ni)
      Lc[wrow * 256 + wcol * 128 + ni * 16 + lane] = csum[ni] * fc;
  }
  __syncthreads();
  // disjoint per-block slots; exact-cover with denred's read bounds.
  if (tid < 128) {
    rowpart[(size_t)(tr * 32u + (c - (tr >> 1))) * 128 + tid] = Lr[tid] + Lr[128 + tid];
  }
  colpart[((size_t)c * 64 + tr) * 256 + tid] = Lc[tid] + Lc[256 + tid];
}

// ---------------- kernel C: reduce partials -> per-128-row log-sums -------
__global__ __launch_bounds__(128) void denred_kernel(const float* __restrict__ rowpart,
                                                     const float* __restrict__ colpart,
                                                     float* __restrict__ lsred) {
  __shared__ float sred2[2];
  const int b = blockIdx.x;  // row-tile tr = b; rows [b*128, b*128+128)
  const int tid = threadIdx.x;
  const int lane = tid & 63, wave = tid >> 6;

  float s = 0.f;
  const int jmax = 32 - (b >> 1);
  const float* rp = rowpart + (size_t)b * 32 * 128 + tid;
  for (int j = 0; j < jmax; ++j) s += rp[j * 128];

  const int cc = b >> 1;  // col-tile of these rows
  const int trmax = (2 * cc + 1 < 63) ? (2 * cc + 1) : 63;
  const float* cpp = colpart + ((size_t)cc * 64) * 256 + (b & 1) * 128 + tid;
  for (int t2 = 0; t2 <= trmax; ++t2) s += cpp[(size_t)t2 * 256];

  float ls = __logf(s - __expf(2.0f));  // remove diagonal self-term e^2
#pragma unroll
  for (int m = 32; m >= 1; m >>= 1) ls += __shfl_xor(ls, m);
  if (lane == 0) sred2[wave] = ls;
  __syncthreads();
  if (tid == 0) lsred[b] = sred2[0] + sred2[1];
}

// ---------------- kernel D: tail (1 block) --------------------------------
__global__ __launch_bounds__(256) void tail_kernel(const float* __restrict__ lsred,
                                                   const float* __restrict__ vsum_part,
                                                   const int* __restrict__ cnt_part,
                                                   const float* __restrict__ ppos,
                                                   float* __restrict__ out) {
  __shared__ float sred[32];
  const int tid = threadIdx.x;
  const int lane = tid & 63, wave = tid >> 6;

  float ls = (tid < 64) ? lsred[tid] : 0.f;
#pragma unroll
  for (int m = 32; m >= 1; m >>= 1) ls += __shfl_xor(ls, m);
  if (lane == 0) sred[wave] = ls;

  float pp = 0.f;
#pragma unroll
  for (int k = 0; k < 4; ++k) pp += ppos[k * 256 + tid];
#pragma unroll
  for (int m = 32; m >= 1; m >>= 1) pp += __shfl_xor(pp, m);
  if (lane == 0) sred[4 + wave] = pp;

  float gp[4];
#pragma unroll
  for (int g = 0; g < 4; ++g) {
    float v = 0.f;
#pragma unroll
    for (int b = 0; b < 16; ++b) v += vsum_part[(size_t)(b * 4 + g) * 256 + tid];
    gp[g] = v * v;
#pragma unroll
    for (int m = 32; m >= 1; m >>= 1) gp[g] += __shfl_xor(gp[g], m);
  }
  if (lane == 0) {
#pragma unroll
    for (int g = 0; g < 4; ++g) sred[8 + wave * 4 + g] = gp[g];
  }
  __syncthreads();
  if (tid == 0) {
    float lsum = sred[0] + sred[1] + sred[2] + sred[3];
    float psum = sred[4] + sred[5] + sred[6] + sred[7];
    float contrastive = (lsum - 4.0f * psum) / (float)TWOB;
    float fsum = 0.f;
    int uniq = 0;
#pragma unroll
    for (int q = 0; q < 4; ++q) {
      int ci = 0;
#pragma unroll
      for (int b = 0; b < 16; ++b) ci += cnt_part[b * 4 + q];
      float gsq = sred[8 + q] + sred[12 + q] + sred[16 + q] + sred[20 + q];
      float cf = (float)ci;
      if (ci > 0) uniq++;
      if (ci > 1) fsum += gsq / (cf * (cf - 1.0f));
    }
    out[0] = contrastive + 0.1f * (fsum / (uniq > 0 ? (float)uniq : 1.0f));
  }
}

extern "C" void kernel_launch(void* const* d_in, const int* in_sizes, int n_in,
                              void* d_out, int out_size, void* d_ws, size_t ws_size,
                              hipStream_t stream) {
  const float* zi = (const float*)d_in[0];
  const float* zj = (const float*)d_in[1];
  const int* sf = (const int*)d_in[2];
  float* out = (float*)d_out;
  char* ws = (char*)d_ws;
  float* lsred = (float*)ws;                            // 64 f32
  float* ppos = (float*)(ws + 1024);                    // 1024 f32
  int* cnt_part = (int*)(ws + 8192);                    // 16x4 int
  float* vsum_part = (float*)(ws + 16384);              // 16x4x256 f32
  unsigned short* znb = (unsigned short*)(ws + 65536);  // 8192x256 bf16 (4MB)
  float* rowpart = (float*)(ws + 4259840);              // 64x32x128 f32 (1MB)
  float* colpart = (float*)(ws + 5308416);              // 32x64x256 f32 (2MB)

  hipLaunchKernelGGL(norm_kernel, dim3(1024), dim3(256), 0, stream, zi, zj, ppos, znb);
  hipLaunchKernelGGL(den_kernel, dim3(64, 17), dim3(256), 0, stream,
                     sf, znb, vsum_part, cnt_part, rowpart, colpart);
  hipLaunchKernelGGL(denred_kernel, dim3(64), dim3(128), 0, stream, rowpart, colpart, lsred);
  hipLaunchKernelGGL(tail_kernel, dim3(1), dim3(256), 0, stream,
                     lsred, vsum_part, cnt_part, ppos, out);
}